// Round 1
// baseline (1469.065 us; speedup 1.0000x reference)
//
#include <hip/hip_runtime.h>

// Problem constants
constexpr int Bsz = 4, Ssz = 2048, Dsz = 1024, Hn = 16, dh = 64, An = 256;

#define TILE 64
#define BK 16
#define PAD 68   // LDS row length in floats: 16B-aligned rows, <=2-way bank conflict

// C[m,n] = scale * sum_k A[m,k]*B[n,k] + bias[n]   (A,B row-major, K contiguous)
// HEADSPLIT=1: write C into [B,H,S,dh] layout (for QKV projections)
template<int HEADSPLIT>
__global__ __launch_bounds__(256)
void gemm_nt(const float* __restrict__ A, const float* __restrict__ B,
             const float* __restrict__ bias, float* __restrict__ C,
             int M, int N, int K,
             long sA, long sB, long sC, float scale)
{
    __shared__ float As[BK][PAD];   // stored transposed: As[k][m]
    __shared__ float Bs[BK][PAD];   // stored transposed: Bs[k][n]
    const int batch = blockIdx.z;
    A += (size_t)batch * sA;
    B += (size_t)batch * sB;
    C += (size_t)batch * sC;
    const int m0 = blockIdx.y * TILE;
    const int n0 = blockIdx.x * TILE;
    const int t  = threadIdx.x;
    const int lr = t >> 2;            // load row 0..63
    const int lc = (t & 3) << 2;      // load col 0,4,8,12
    const int tx = t & 15, ty = t >> 4;

    float acc[4][4] = {};

    for (int k0 = 0; k0 < K; k0 += BK) {
        float4 a4 = *reinterpret_cast<const float4*>(A + (size_t)(m0 + lr) * K + k0 + lc);
        float4 b4 = *reinterpret_cast<const float4*>(B + (size_t)(n0 + lr) * K + k0 + lc);
        __syncthreads();
        As[lc+0][lr] = a4.x; As[lc+1][lr] = a4.y; As[lc+2][lr] = a4.z; As[lc+3][lr] = a4.w;
        Bs[lc+0][lr] = b4.x; Bs[lc+1][lr] = b4.y; Bs[lc+2][lr] = b4.z; Bs[lc+3][lr] = b4.w;
        __syncthreads();
        #pragma unroll
        for (int kk = 0; kk < BK; ++kk) {
            float4 av = *reinterpret_cast<const float4*>(&As[kk][ty << 2]);
            float4 bv = *reinterpret_cast<const float4*>(&Bs[kk][tx << 2]);
            const float a[4] = {av.x, av.y, av.z, av.w};
            const float b[4] = {bv.x, bv.y, bv.z, bv.w};
            #pragma unroll
            for (int i = 0; i < 4; ++i)
                #pragma unroll
                for (int j = 0; j < 4; ++j)
                    acc[i][j] = fmaf(a[i], b[j], acc[i][j]);
        }
    }

    #pragma unroll
    for (int i = 0; i < 4; ++i) {
        const int m = m0 + (ty << 2) + i;
        #pragma unroll
        for (int j = 0; j < 4; ++j) {
            const int n = n0 + (tx << 2) + j;
            float val = acc[i][j] * scale + (bias ? bias[n] : 0.0f);
            if constexpr (HEADSPLIT) {
                const int b = m >> 11, s = m & (Ssz - 1);
                const int h = n >> 6,  c = n & (dh - 1);
                C[(((size_t)(b * Hn + h)) * Ssz + s) * dh + c] = val;
            } else {
                C[(size_t)m * N + n] = val;
            }
        }
    }
}

// C[m,n] = sum_k A[m,k]*B[k,n]   (A row-major K-contig, B row-major N-contig)
// HEADMERGE=1: batch index is bh; write into flat [B,S,D] at column h*dh+n
template<int HEADMERGE>
__global__ __launch_bounds__(256)
void gemm_nn(const float* __restrict__ A, const float* __restrict__ B,
             float* __restrict__ C, int M, int N, int K,
             long sA, long sB, long sC)
{
    __shared__ float As[BK][PAD];   // As[k][m]
    __shared__ float Bs[BK][PAD];   // Bs[k][n] (natural)
    const int batch = blockIdx.z;
    A += (size_t)batch * sA;
    B += (size_t)batch * sB;
    const int m0 = blockIdx.y * TILE;
    const int n0 = blockIdx.x * TILE;
    const int t  = threadIdx.x;
    const int lr = t >> 2,  lc = (t & 3) << 2;
    const int br = t >> 4,  bc = (t & 15) << 2;
    const int tx = t & 15,  ty = t >> 4;

    float acc[4][4] = {};

    for (int k0 = 0; k0 < K; k0 += BK) {
        float4 a4 = *reinterpret_cast<const float4*>(A + (size_t)(m0 + lr) * K + k0 + lc);
        float4 b4 = *reinterpret_cast<const float4*>(B + (size_t)(k0 + br) * N + n0 + bc);
        __syncthreads();
        As[lc+0][lr] = a4.x; As[lc+1][lr] = a4.y; As[lc+2][lr] = a4.z; As[lc+3][lr] = a4.w;
        *reinterpret_cast<float4*>(&Bs[br][bc]) = b4;
        __syncthreads();
        #pragma unroll
        for (int kk = 0; kk < BK; ++kk) {
            float4 av = *reinterpret_cast<const float4*>(&As[kk][ty << 2]);
            float4 bv = *reinterpret_cast<const float4*>(&Bs[kk][tx << 2]);
            const float a[4] = {av.x, av.y, av.z, av.w};
            const float b[4] = {bv.x, bv.y, bv.z, bv.w};
            #pragma unroll
            for (int i = 0; i < 4; ++i)
                #pragma unroll
                for (int j = 0; j < 4; ++j)
                    acc[i][j] = fmaf(a[i], b[j], acc[i][j]);
        }
    }

    #pragma unroll
    for (int i = 0; i < 4; ++i) {
        const int m = m0 + (ty << 2) + i;
        #pragma unroll
        for (int j = 0; j < 4; ++j) {
            const int n = n0 + (tx << 2) + j;
            if constexpr (HEADMERGE) {
                const int b = batch >> 4, h = batch & (Hn - 1);
                C[((size_t)(b * Ssz + m)) * Dsz + h * dh + n] = acc[i][j];
            } else {
                (C + (size_t)batch * sC)[(size_t)m * N + n] = acc[i][j];
            }
        }
    }
}

// agent[bh, a, c] = mean_{j<8} qh[bh, a*8+j, c]
__global__ __launch_bounds__(256)
void pool_agent(const float* __restrict__ qh, float* __restrict__ agent)
{
    const int idx = blockIdx.x * 256 + threadIdx.x;   // < 64*256*64 = 1048576
    const int c  = idx & (dh - 1);
    const int a  = (idx >> 6) & (An - 1);
    const int bh = idx >> 14;
    const float* p = qh + ((size_t)bh * Ssz + a * 8) * dh + c;
    float s = 0.f;
    #pragma unroll
    for (int j = 0; j < 8; ++j) s += p[j * dh];
    agent[idx] = s * 0.125f;
}

// in-place row softmax, one block per row
__global__ __launch_bounds__(256)
void softmax_rows(float* __restrict__ data, int L)
{
    __shared__ float red[256];
    float* p = data + (size_t)blockIdx.x * L;
    const int t = threadIdx.x;

    float m = -INFINITY;
    for (int i = t; i < L; i += 256) m = fmaxf(m, p[i]);
    red[t] = m; __syncthreads();
    for (int s = 128; s > 0; s >>= 1) { if (t < s) red[t] = fmaxf(red[t], red[t + s]); __syncthreads(); }
    m = red[0]; __syncthreads();

    float sum = 0.f;
    for (int i = t; i < L; i += 256) { float e = expf(p[i] - m); p[i] = e; sum += e; }
    red[t] = sum; __syncthreads();
    for (int s = 128; s > 0; s >>= 1) { if (t < s) red[t] += red[t + s]; __syncthreads(); }
    const float inv = 1.0f / red[0];

    for (int i = t; i < L; i += 256) p[i] *= inv;
}

extern "C" void kernel_launch(void* const* d_in, const int* in_sizes, int n_in,
                              void* d_out, int out_size, void* d_ws, size_t ws_size,
                              hipStream_t stream)
{
    const float* q  = (const float*)d_in[0];
    const float* k  = (const float*)d_in[1];
    const float* v  = (const float*)d_in[2];
    const float* Wq = (const float*)d_in[3];
    const float* bq = (const float*)d_in[4];
    const float* Wk = (const float*)d_in[5];
    const float* bk = (const float*)d_in[6];
    const float* Wv = (const float*)d_in[7];
    const float* bv = (const float*)d_in[8];
    const float* Wo = (const float*)d_in[9];
    const float* bo = (const float*)d_in[10];

    constexpr size_t BSD  = (size_t)Bsz * Ssz * Dsz;      // 8,388,608
    constexpr size_t BHSA = (size_t)Bsz * Hn * Ssz * An;  // 33,554,432
    constexpr size_t BHAd = (size_t)Bsz * Hn * An * dh;   // 1,048,576

    float* out    = (float*)d_out;          // [B,S,D]
    float* q_attn = out + BSD;              // [B,H,S,A]; also stage-1 scratch

    float* ws      = (float*)d_ws;
    float* qh      = ws;                    // [B,H,S,dh]
    float* kh      = qh + BSD;
    float* vh      = kh + BSD;
    float* agent   = vh + BSD;              // [B,H,A,dh]
    float* agent_v = agent + BHAd;          // [B,H,A,dh]
    float* out_h   = agent_v + BHAd;        // [B,S,D] (head-merged)

    const float scale = 0.125f;             // 1/sqrt(64)
    const int M = Bsz * Ssz;                // 8192

    // 1) QKV projections (head-split outputs)
    dim3 gproj(Dsz / TILE, M / TILE, 1);
    gemm_nt<1><<<gproj, 256, 0, stream>>>(q, Wq, bq, qh, M, Dsz, Dsz, 0, 0, 0, 1.0f);
    gemm_nt<1><<<gproj, 256, 0, stream>>>(k, Wk, bk, kh, M, Dsz, Dsz, 0, 0, 0, 1.0f);
    gemm_nt<1><<<gproj, 256, 0, stream>>>(v, Wv, bv, vh, M, Dsz, Dsz, 0, 0, 0, 1.0f);

    // 2) agent pooling
    pool_agent<<<BHAd / 256, 256, 0, stream>>>(qh, agent);

    // 3) stage-1 scores: [bh,256,2048] into q_attn region as scratch
    gemm_nt<0><<<dim3(Ssz / TILE, An / TILE, 64), 256, 0, stream>>>(
        agent, kh, nullptr, q_attn, An, Ssz, dh,
        (long)An * dh, (long)Ssz * dh, (long)An * Ssz, scale);

    // 4) softmax over S
    softmax_rows<<<64 * An, 256, 0, stream>>>(q_attn, Ssz);

    // 5) agent_v = attn @ vh : [bh,256,64]
    gemm_nn<0><<<dim3(1, An / TILE, 64), 256, 0, stream>>>(
        q_attn, vh, agent_v, An, dh, Ssz,
        (long)An * Ssz, (long)Ssz * dh, (long)An * dh);

    // 6) stage-2 scores: q_attn = qh @ agent^T : [bh,2048,256]
    gemm_nt<0><<<dim3(An / TILE, Ssz / TILE, 64), 256, 0, stream>>>(
        qh, agent, nullptr, q_attn, Ssz, An, dh,
        (long)Ssz * dh, (long)An * dh, (long)Ssz * An, scale);

    // 7) softmax over A
    softmax_rows<<<64 * Ssz, 256, 0, stream>>>(q_attn, An);

    // 8) out_h = q_attn @ agent_v, head-merged into [B,S,D]
    gemm_nn<1><<<dim3(1, Ssz / TILE, 64), 256, 0, stream>>>(
        q_attn, agent_v, out_h, Ssz, dh, An,
        (long)Ssz * An, (long)An * dh, 0);

    // 9) output projection
    gemm_nt<0><<<gproj, 256, 0, stream>>>(out_h, Wo, bo, out, M, Dsz, Dsz, 0, 0, 0, 1.0f);
}

// Round 2
// 802.103 us; speedup vs baseline: 1.8315x; 1.8315x over previous
//
#include <hip/hip_runtime.h>

// Problem constants
constexpr int Bsz = 4, Ssz = 2048, Dsz = 1024, Hn = 16, dh = 64, An = 256;

typedef __attribute__((ext_vector_type(8))) short bf16x8;
typedef __attribute__((ext_vector_type(4))) float f32x4;
typedef unsigned short ushortT;

// ---------- helpers ----------
__device__ __forceinline__ unsigned short f2bf_rn(float f) {
    unsigned int u = __float_as_uint(f);
    unsigned int r = (u + 0x7FFFu + ((u >> 16) & 1u)) >> 16;
    return (unsigned short)r;
}
__device__ __forceinline__ void bf_split(float f, unsigned short& hi, unsigned short& lo) {
    hi = f2bf_rn(f);
    float fh = __uint_as_float(((unsigned int)hi) << 16);
    lo = f2bf_rn(f - fh);
}

__device__ __forceinline__ void gload_lds16(const unsigned short* g, unsigned short* l) {
    __builtin_amdgcn_global_load_lds(
        (const __attribute__((address_space(1))) unsigned int*)g,
        (__attribute__((address_space(3))) unsigned int*)l, 16, 0, 0);
}

// fp32 [n4*4] -> bf16 hi/lo arrays
__global__ __launch_bounds__(256)
void split_kernel(const float* __restrict__ x, unsigned short* __restrict__ hi,
                  unsigned short* __restrict__ lo, int n4)
{
    int i = blockIdx.x * 256 + threadIdx.x;
    if (i >= n4) return;
    float4 v = reinterpret_cast<const float4*>(x)[i];
    ushort4 h, l;
    bf_split(v.x, h.x, l.x);
    bf_split(v.y, h.y, l.y);
    bf_split(v.z, h.z, l.z);
    bf_split(v.w, h.w, l.w);
    reinterpret_cast<ushort4*>(hi)[i] = h;
    reinterpret_cast<ushort4*>(lo)[i] = l;
}

// ---------- split-bf16 MFMA GEMM: C[m,n] = sum_k A[m,k]*B[n,k] + bias[n] ----------
// A,B given as hi/lo bf16 row-major [*, K] (K contiguous). 128x128 tile, BK=32.
// HEADSPLIT=1: write C into [B,H,S,dh] layout.
#define MT 128
#define BKm 32

// read one 16x32 A/B fragment (bf16x8 per lane) from a [128][32] bf16 LDS buffer
// with chunk swizzle: chunk_read = c ^ ((row>>1)&3)
__device__ __forceinline__ bf16x8 lds_frag(const unsigned short* buf, int baseRow, int lane) {
    int row = baseRow + (lane & 15);
    int c = lane >> 4;
    int idx = row * 32 + ((c ^ ((row >> 1) & 3)) << 3);
    return *reinterpret_cast<const bf16x8*>(buf + idx);
}

template<int HEADSPLIT>
__global__ __launch_bounds__(256, 2)
void gemm_nt_mfma3(const unsigned short* __restrict__ Ahi, const unsigned short* __restrict__ Alo,
                   const unsigned short* __restrict__ Bhi, const unsigned short* __restrict__ Blo,
                   const float* __restrict__ bias, float* __restrict__ C,
                   int K, int N)
{
    __shared__ unsigned short lds[4 * 4096];  // [Ahi|Alo|Bhi|Blo] each [128][32] bf16
    const int t = threadIdx.x;
    const int lane = t & 63, wid = t >> 6;
    const int wr = wid >> 1, wc = wid & 1;
    const int m0 = blockIdx.y * MT, n0 = blockIdx.x * MT;

    // staging geometry: per buffer, 2 issues of 256 lanes x 16B
    const int srow0 = t >> 2;            // issue 0 row
    const int x4 = t & 3;                // linear chunk
    // wave-uniform LDS base offsets (ushort units): (issue*256 + wid*64) * 8
    const int ldsBase0 = (wid * 64) * 8;
    const int ldsBase1 = (256 + wid * 64) * 8;

    f32x4 acc[4][4];
    #pragma unroll
    for (int i = 0; i < 4; ++i)
        #pragma unroll
        for (int j = 0; j < 4; ++j)
            acc[i][j] = f32x4{0.f, 0.f, 0.f, 0.f};

    const unsigned short* gA[2] = {Ahi, Alo};
    const unsigned short* gB[2] = {Bhi, Blo};

    for (int k0 = 0; k0 < K; k0 += BKm) {
        // ---- stage 4 buffers ----
        #pragma unroll
        for (int hb = 0; hb < 2; ++hb) {
            {   // A buffer hb, issues 0 and 1
                const unsigned short* G = gA[hb];
                int r0 = srow0, r1 = srow0 + 64;
                int c0 = x4 ^ ((r0 >> 1) & 3);
                int c1 = x4 ^ ((r1 >> 1) & 3);
                gload_lds16(G + (size_t)(m0 + r0) * K + k0 + c0 * 8, lds + hb * 4096 + ldsBase0);
                gload_lds16(G + (size_t)(m0 + r1) * K + k0 + c1 * 8, lds + hb * 4096 + ldsBase1);
            }
            {   // B buffer hb
                const unsigned short* G = gB[hb];
                int r0 = srow0, r1 = srow0 + 64;
                int c0 = x4 ^ ((r0 >> 1) & 3);
                int c1 = x4 ^ ((r1 >> 1) & 3);
                gload_lds16(G + (size_t)(n0 + r0) * K + k0 + c0 * 8, lds + (2 + hb) * 4096 + ldsBase0);
                gload_lds16(G + (size_t)(n0 + r1) * K + k0 + c1 * 8, lds + (2 + hb) * 4096 + ldsBase1);
            }
        }
        __syncthreads();   // drains vmcnt(0) before barrier

        // ---- fragments ----
        bf16x8 ah[4], al[4], bh[4], bl[4];
        #pragma unroll
        for (int mi = 0; mi < 4; ++mi) {
            ah[mi] = lds_frag(lds + 0 * 4096, wr * 64 + mi * 16, lane);
            al[mi] = lds_frag(lds + 1 * 4096, wr * 64 + mi * 16, lane);
        }
        #pragma unroll
        for (int ni = 0; ni < 4; ++ni) {
            bh[ni] = lds_frag(lds + 2 * 4096, wc * 64 + ni * 16, lane);
            bl[ni] = lds_frag(lds + 3 * 4096, wc * 64 + ni * 16, lane);
        }
        // ---- 3-term MFMA ----
        #pragma unroll
        for (int mi = 0; mi < 4; ++mi)
            #pragma unroll
            for (int ni = 0; ni < 4; ++ni) {
                acc[mi][ni] = __builtin_amdgcn_mfma_f32_16x16x32_bf16(ah[mi], bh[ni], acc[mi][ni], 0, 0, 0);
                acc[mi][ni] = __builtin_amdgcn_mfma_f32_16x16x32_bf16(ah[mi], bl[ni], acc[mi][ni], 0, 0, 0);
                acc[mi][ni] = __builtin_amdgcn_mfma_f32_16x16x32_bf16(al[mi], bh[ni], acc[mi][ni], 0, 0, 0);
            }
        __syncthreads();
    }

    // ---- epilogue ----
    #pragma unroll
    for (int mi = 0; mi < 4; ++mi) {
        #pragma unroll
        for (int ni = 0; ni < 4; ++ni) {
            const int n = n0 + wc * 64 + ni * 16 + (lane & 15);
            const float bval = bias[n];
            #pragma unroll
            for (int j = 0; j < 4; ++j) {
                const int m = m0 + wr * 64 + mi * 16 + ((lane >> 4) << 2) + j;
                float val = acc[mi][ni][j] + bval;
                if constexpr (HEADSPLIT) {
                    const int b = m >> 11, s = m & (Ssz - 1);
                    const int h = n >> 6, c = n & (dh - 1);
                    C[(((size_t)(b * Hn + h)) * Ssz + s) * dh + c] = val;
                } else {
                    C[(size_t)m * N + n] = val;
                }
            }
        }
    }
}

// ---------- fp32 tiled GEMMs (attention path) ----------
#define TILE 64
#define BK 16
#define PAD 68

__global__ __launch_bounds__(256)
void gemm_nt(const float* __restrict__ A, const float* __restrict__ B,
             float* __restrict__ C, int M, int N, int K,
             long sA, long sB, long sC, float scale)
{
    __shared__ float As[BK][PAD];
    __shared__ float Bs[BK][PAD];
    const int batch = blockIdx.z;
    A += (size_t)batch * sA;
    B += (size_t)batch * sB;
    C += (size_t)batch * sC;
    const int m0 = blockIdx.y * TILE;
    const int n0 = blockIdx.x * TILE;
    const int t = threadIdx.x;
    const int lr = t >> 2, lc = (t & 3) << 2;
    const int tx = t & 15, ty = t >> 4;

    float acc[4][4] = {};

    for (int k0 = 0; k0 < K; k0 += BK) {
        float4 a4 = *reinterpret_cast<const float4*>(A + (size_t)(m0 + lr) * K + k0 + lc);
        float4 b4 = *reinterpret_cast<const float4*>(B + (size_t)(n0 + lr) * K + k0 + lc);
        __syncthreads();
        As[lc+0][lr] = a4.x; As[lc+1][lr] = a4.y; As[lc+2][lr] = a4.z; As[lc+3][lr] = a4.w;
        Bs[lc+0][lr] = b4.x; Bs[lc+1][lr] = b4.y; Bs[lc+2][lr] = b4.z; Bs[lc+3][lr] = b4.w;
        __syncthreads();
        #pragma unroll
        for (int kk = 0; kk < BK; ++kk) {
            float4 av = *reinterpret_cast<const float4*>(&As[kk][ty << 2]);
            float4 bv = *reinterpret_cast<const float4*>(&Bs[kk][tx << 2]);
            const float a[4] = {av.x, av.y, av.z, av.w};
            const float b[4] = {bv.x, bv.y, bv.z, bv.w};
            #pragma unroll
            for (int i = 0; i < 4; ++i)
                #pragma unroll
                for (int j = 0; j < 4; ++j)
                    acc[i][j] = fmaf(a[i], b[j], acc[i][j]);
        }
    }

    #pragma unroll
    for (int i = 0; i < 4; ++i) {
        const int m = m0 + (ty << 2) + i;
        #pragma unroll
        for (int j = 0; j < 4; ++j) {
            const int n = n0 + (tx << 2) + j;
            C[(size_t)m * N + n] = acc[i][j] * scale;
        }
    }
}

// MODE 0: plain fp32 C[batch]; MODE 1: head-merge + bf16-split output (Chi/Clo at [B,S,D])
template<int MODE>
__global__ __launch_bounds__(256)
void gemm_nn(const float* __restrict__ A, const float* __restrict__ B,
             float* __restrict__ C, unsigned short* __restrict__ Chi,
             unsigned short* __restrict__ Clo, int M, int N, int K,
             long sA, long sB, long sC)
{
    __shared__ float As[BK][PAD];
    __shared__ float Bs[BK][PAD];
    const int batch = blockIdx.z;
    A += (size_t)batch * sA;
    B += (size_t)batch * sB;
    const int m0 = blockIdx.y * TILE;
    const int n0 = blockIdx.x * TILE;
    const int t = threadIdx.x;
    const int lr = t >> 2, lc = (t & 3) << 2;
    const int br = t >> 4, bc = (t & 15) << 2;
    const int tx = t & 15, ty = t >> 4;

    float acc[4][4] = {};

    for (int k0 = 0; k0 < K; k0 += BK) {
        float4 a4 = *reinterpret_cast<const float4*>(A + (size_t)(m0 + lr) * K + k0 + lc);
        float4 b4 = *reinterpret_cast<const float4*>(B + (size_t)(k0 + br) * N + n0 + bc);
        __syncthreads();
        As[lc+0][lr] = a4.x; As[lc+1][lr] = a4.y; As[lc+2][lr] = a4.z; As[lc+3][lr] = a4.w;
        *reinterpret_cast<float4*>(&Bs[br][bc]) = b4;
        __syncthreads();
        #pragma unroll
        for (int kk = 0; kk < BK; ++kk) {
            float4 av = *reinterpret_cast<const float4*>(&As[kk][ty << 2]);
            float4 bv = *reinterpret_cast<const float4*>(&Bs[kk][tx << 2]);
            const float a[4] = {av.x, av.y, av.z, av.w};
            const float b[4] = {bv.x, bv.y, bv.z, bv.w};
            #pragma unroll
            for (int i = 0; i < 4; ++i)
                #pragma unroll
                for (int j = 0; j < 4; ++j)
                    acc[i][j] = fmaf(a[i], b[j], acc[i][j]);
        }
    }

    #pragma unroll
    for (int i = 0; i < 4; ++i) {
        const int m = m0 + (ty << 2) + i;
        #pragma unroll
        for (int j = 0; j < 4; ++j) {
            const int n = n0 + (tx << 2) + j;
            if constexpr (MODE == 1) {
                const int b = batch >> 4, h = batch & (Hn - 1);
                size_t idx = ((size_t)(b * Ssz + m)) * Dsz + h * dh + n;
                unsigned short hi, lo;
                bf_split(acc[i][j], hi, lo);
                Chi[idx] = hi; Clo[idx] = lo;
            } else {
                (C + (size_t)batch * sC)[(size_t)m * N + n] = acc[i][j];
            }
        }
    }
}

// agent[bh, a, c] = mean_{j<8} qh[bh, a*8+j, c]
__global__ __launch_bounds__(256)
void pool_agent(const float* __restrict__ qh, float* __restrict__ agent)
{
    const int idx = blockIdx.x * 256 + threadIdx.x;
    const int c = idx & (dh - 1);
    const int a = (idx >> 6) & (An - 1);
    const int bh = idx >> 14;
    const float* p = qh + ((size_t)bh * Ssz + a * 8) * dh + c;
    float s = 0.f;
    #pragma unroll
    for (int j = 0; j < 8; ++j) s += p[j * dh];
    agent[idx] = s * 0.125f;
}

__global__ __launch_bounds__(256)
void softmax_rows(float* __restrict__ data, int L)
{
    __shared__ float red[256];
    float* p = data + (size_t)blockIdx.x * L;
    const int t = threadIdx.x;

    float m = -INFINITY;
    for (int i = t; i < L; i += 256) m = fmaxf(m, p[i]);
    red[t] = m; __syncthreads();
    for (int s = 128; s > 0; s >>= 1) { if (t < s) red[t] = fmaxf(red[t], red[t + s]); __syncthreads(); }
    m = red[0]; __syncthreads();

    float sum = 0.f;
    for (int i = t; i < L; i += 256) { float e = expf(p[i] - m); p[i] = e; sum += e; }
    red[t] = sum; __syncthreads();
    for (int s = 128; s > 0; s >>= 1) { if (t < s) red[t] += red[t + s]; __syncthreads(); }
    const float inv = 1.0f / red[0];

    for (int i = t; i < L; i += 256) p[i] *= inv;
}

extern "C" void kernel_launch(void* const* d_in, const int* in_sizes, int n_in,
                              void* d_out, int out_size, void* d_ws, size_t ws_size,
                              hipStream_t stream)
{
    const float* q  = (const float*)d_in[0];
    const float* k  = (const float*)d_in[1];
    const float* v  = (const float*)d_in[2];
    const float* Wq = (const float*)d_in[3];
    const float* bq = (const float*)d_in[4];
    const float* Wk = (const float*)d_in[5];
    const float* bk = (const float*)d_in[6];
    const float* Wv = (const float*)d_in[7];
    const float* bv = (const float*)d_in[8];
    const float* Wo = (const float*)d_in[9];
    const float* bo = (const float*)d_in[10];

    constexpr size_t BSD  = (size_t)Bsz * Ssz * Dsz;      // 8,388,608
    constexpr size_t BHAd = (size_t)Bsz * Hn * An * dh;   // 1,048,576
    constexpr size_t DD   = (size_t)Dsz * Dsz;            // 1,048,576

    float* out    = (float*)d_out;
    float* q_attn = out + BSD;

    float* ws      = (float*)d_ws;
    float* qh      = ws;
    float* kh      = qh + BSD;
    float* vh      = kh + BSD;
    float* agent   = vh + BSD;
    float* agent_v = agent + BHAd;
    unsigned short* x_hi = (unsigned short*)(agent_v + BHAd);
    unsigned short* x_lo = x_hi + BSD;
    unsigned short* w_hi = x_lo + BSD;
    unsigned short* w_lo = w_hi + DD;

    const float scale = 0.125f;
    const int M = Bsz * Ssz;             // 8192
    dim3 gmfma(Dsz / MT, M / MT, 1);     // (8, 64)

    // 1) Q projection
    split_kernel<<<(BSD/4 + 255)/256, 256, 0, stream>>>(q, x_hi, x_lo, BSD/4);
    split_kernel<<<(DD/4 + 255)/256, 256, 0, stream>>>(Wq, w_hi, w_lo, DD/4);
    gemm_nt_mfma3<1><<<gmfma, 256, 0, stream>>>(x_hi, x_lo, w_hi, w_lo, bq, qh, Dsz, Dsz);
    // 2) K projection
    split_kernel<<<(BSD/4 + 255)/256, 256, 0, stream>>>(k, x_hi, x_lo, BSD/4);
    split_kernel<<<(DD/4 + 255)/256, 256, 0, stream>>>(Wk, w_hi, w_lo, DD/4);
    gemm_nt_mfma3<1><<<gmfma, 256, 0, stream>>>(x_hi, x_lo, w_hi, w_lo, bk, kh, Dsz, Dsz);
    // 3) V projection
    split_kernel<<<(BSD/4 + 255)/256, 256, 0, stream>>>(v, x_hi, x_lo, BSD/4);
    split_kernel<<<(DD/4 + 255)/256, 256, 0, stream>>>(Wv, w_hi, w_lo, DD/4);
    gemm_nt_mfma3<1><<<gmfma, 256, 0, stream>>>(x_hi, x_lo, w_hi, w_lo, bv, vh, Dsz, Dsz);

    // 4) agent pooling
    pool_agent<<<BHAd / 256, 256, 0, stream>>>(qh, agent);

    // 5) stage-1 scores: [bh,256,2048] into q_attn region as scratch
    gemm_nt<<<dim3(Ssz / TILE, An / TILE, 64), 256, 0, stream>>>(
        agent, kh, q_attn, An, Ssz, dh,
        (long)An * dh, (long)Ssz * dh, (long)An * Ssz, scale);

    // 6) softmax over S
    softmax_rows<<<64 * An, 256, 0, stream>>>(q_attn, Ssz);

    // 7) agent_v = attn @ vh
    gemm_nn<0><<<dim3(1, An / TILE, 64), 256, 0, stream>>>(
        q_attn, vh, agent_v, nullptr, nullptr, An, dh, Ssz,
        (long)An * Ssz, (long)Ssz * dh, (long)An * dh);

    // 8) stage-2 scores: q_attn = qh @ agent^T
    gemm_nt<<<dim3(An / TILE, Ssz / TILE, 64), 256, 0, stream>>>(
        qh, agent, q_attn, Ssz, An, dh,
        (long)Ssz * dh, (long)An * dh, (long)Ssz * An, scale);

    // 9) softmax over A
    softmax_rows<<<64 * Ssz, 256, 0, stream>>>(q_attn, An);

    // 10) out_h = q_attn @ agent_v, head-merged, bf16-split into x_hi/x_lo
    gemm_nn<1><<<dim3(1, Ssz / TILE, 64), 256, 0, stream>>>(
        q_attn, agent_v, nullptr, x_hi, x_lo, Ssz, dh, An,
        (long)Ssz * An, (long)An * dh, 0);

    // 11) output projection (MFMA split-bf16)
    split_kernel<<<(DD/4 + 255)/256, 256, 0, stream>>>(Wo, w_hi, w_lo, DD/4);
    gemm_nt_mfma3<0><<<gmfma, 256, 0, stream>>>(x_hi, x_lo, w_hi, w_lo, bo, out, Dsz, Dsz);
}

// Round 3
// 421.009 us; speedup vs baseline: 3.4894x; 1.9052x over previous
//
#include <hip/hip_runtime.h>

// Problem constants
constexpr int Bsz = 4, Ssz = 2048, Dsz = 1024, Hn = 16, dh = 64, An = 256;

typedef __attribute__((ext_vector_type(8))) short bf16x8;
typedef __attribute__((ext_vector_type(4))) float f32x4;

// ---------- helpers ----------
__device__ __forceinline__ unsigned short f2bf_rn(float f) {
    unsigned int u = __float_as_uint(f);
    return (unsigned short)((u + 0x7FFFu + ((u >> 16) & 1u)) >> 16);
}
__device__ __forceinline__ float bf2f(unsigned short h) {
    return __uint_as_float(((unsigned int)h) << 16);
}
__device__ __forceinline__ void bf_split(float f, unsigned short& hi, unsigned short& lo) {
    hi = f2bf_rn(f);
    lo = f2bf_rn(f - bf2f(hi));
}
__device__ __forceinline__ void gload16(const unsigned short* g, unsigned short* l) {
    __builtin_amdgcn_global_load_lds(
        (const __attribute__((address_space(1))) unsigned int*)g,
        (__attribute__((address_space(3))) unsigned int*)l, 16, 0, 0);
}

// Stage a tile of rows x (8*2^LOGC-elem) rows into linear LDS with source-side
// chunk swizzle (chunk_src = c ^ (row&7)); fragR reads with the same XOR.
template<int LOGC, int NISS>
__device__ __forceinline__ void stage_tile(const unsigned short* __restrict__ g, long rowStride,
                                           unsigned short* lbase, int t) {
    const int wid = t >> 6;
    #pragma unroll
    for (int i = 0; i < NISS; ++i) {
        int slot = i * 256 + t;
        int r = slot >> LOGC;
        int c = slot & ((1 << LOGC) - 1);
        int cs = (c ^ (r & 7)) & ((1 << LOGC) - 1);
        gload16(g + (long)r * rowStride + cs * 8, lbase + (i * 256 + wid * 64) * 8);
    }
}

// Read one 16-row x 32-k fragment (k-step ks) from a [*][ROWLEN] bf16 LDS tile.
template<int ROWLEN>
__device__ __forceinline__ bf16x8 fragR(const unsigned short* buf, int row, int ks, int lane) {
    int c = ks * 4 + (lane >> 4);
    int cs = (c ^ (row & 7)) & (ROWLEN / 8 - 1);
    return *reinterpret_cast<const bf16x8*>(buf + row * ROWLEN + cs * 8);
}

// fp32 [n4*4] -> bf16 hi/lo arrays
__global__ __launch_bounds__(256)
void split_kernel(const float* __restrict__ x, unsigned short* __restrict__ hi,
                  unsigned short* __restrict__ lo, int n4)
{
    int i = blockIdx.x * 256 + threadIdx.x;
    if (i >= n4) return;
    float4 v = reinterpret_cast<const float4*>(x)[i];
    ushort4 h, l;
    bf_split(v.x, h.x, l.x);
    bf_split(v.y, h.y, l.y);
    bf_split(v.z, h.z, l.z);
    bf_split(v.w, h.w, l.w);
    reinterpret_cast<ushort4*>(hi)[i] = h;
    reinterpret_cast<ushort4*>(lo)[i] = l;
}

// ---------- split-bf16 MFMA GEMM: C[m,n] = sum_k A[m,k]*B[n,k] + bias[n] ----------
// OMODE 0: fp32 flat [M][N]. OMODE 1: split bf16 head-split [B,H,S,dh].
// OMODE 2: split bf16 head-split TRANSPOSED [B,H,dh,S].
#define MT 128
#define BKm 32

__device__ __forceinline__ bf16x8 lds_frag(const unsigned short* buf, int baseRow, int lane) {
    int row = baseRow + (lane & 15);
    int c = lane >> 4;
    int idx = row * 32 + ((c ^ ((row >> 1) & 3)) << 3);
    return *reinterpret_cast<const bf16x8*>(buf + idx);
}

template<int OMODE>
__global__ __launch_bounds__(256, 2)
void gemm_nt_mfma3(const unsigned short* __restrict__ Ahi, const unsigned short* __restrict__ Alo,
                   const unsigned short* __restrict__ Bhi, const unsigned short* __restrict__ Blo,
                   const float* __restrict__ bias, float* __restrict__ Cf,
                   unsigned short* __restrict__ Chi, unsigned short* __restrict__ Clo,
                   int K, int N)
{
    __shared__ unsigned short lds[4 * 4096];
    const int t = threadIdx.x;
    const int lane = t & 63, wid = t >> 6;
    const int wr = wid >> 1, wc = wid & 1;
    const int m0 = blockIdx.y * MT, n0 = blockIdx.x * MT;

    const int srow0 = t >> 2;
    const int x4 = t & 3;
    const int ldsBase0 = (wid * 64) * 8;
    const int ldsBase1 = (256 + wid * 64) * 8;

    f32x4 acc[4][4];
    #pragma unroll
    for (int i = 0; i < 4; ++i)
        #pragma unroll
        for (int j = 0; j < 4; ++j)
            acc[i][j] = f32x4{0.f, 0.f, 0.f, 0.f};

    const unsigned short* gA[2] = {Ahi, Alo};
    const unsigned short* gB[2] = {Bhi, Blo};

    for (int k0 = 0; k0 < K; k0 += BKm) {
        #pragma unroll
        for (int hb = 0; hb < 2; ++hb) {
            {
                const unsigned short* G = gA[hb];
                int r0 = srow0, r1 = srow0 + 64;
                int c0 = x4 ^ ((r0 >> 1) & 3);
                int c1 = x4 ^ ((r1 >> 1) & 3);
                gload16(G + (size_t)(m0 + r0) * K + k0 + c0 * 8, lds + hb * 4096 + ldsBase0);
                gload16(G + (size_t)(m0 + r1) * K + k0 + c1 * 8, lds + hb * 4096 + ldsBase1);
            }
            {
                const unsigned short* G = gB[hb];
                int r0 = srow0, r1 = srow0 + 64;
                int c0 = x4 ^ ((r0 >> 1) & 3);
                int c1 = x4 ^ ((r1 >> 1) & 3);
                gload16(G + (size_t)(n0 + r0) * K + k0 + c0 * 8, lds + (2 + hb) * 4096 + ldsBase0);
                gload16(G + (size_t)(n0 + r1) * K + k0 + c1 * 8, lds + (2 + hb) * 4096 + ldsBase1);
            }
        }
        __syncthreads();

        bf16x8 ah[4], al[4], bh[4], bl[4];
        #pragma unroll
        for (int mi = 0; mi < 4; ++mi) {
            ah[mi] = lds_frag(lds + 0 * 4096, wr * 64 + mi * 16, lane);
            al[mi] = lds_frag(lds + 1 * 4096, wr * 64 + mi * 16, lane);
        }
        #pragma unroll
        for (int ni = 0; ni < 4; ++ni) {
            bh[ni] = lds_frag(lds + 2 * 4096, wc * 64 + ni * 16, lane);
            bl[ni] = lds_frag(lds + 3 * 4096, wc * 64 + ni * 16, lane);
        }
        #pragma unroll
        for (int mi = 0; mi < 4; ++mi)
            #pragma unroll
            for (int ni = 0; ni < 4; ++ni) {
                acc[mi][ni] = __builtin_amdgcn_mfma_f32_16x16x32_bf16(ah[mi], bh[ni], acc[mi][ni], 0, 0, 0);
                acc[mi][ni] = __builtin_amdgcn_mfma_f32_16x16x32_bf16(ah[mi], bl[ni], acc[mi][ni], 0, 0, 0);
                acc[mi][ni] = __builtin_amdgcn_mfma_f32_16x16x32_bf16(al[mi], bh[ni], acc[mi][ni], 0, 0, 0);
            }
        __syncthreads();
    }

    #pragma unroll
    for (int mi = 0; mi < 4; ++mi) {
        #pragma unroll
        for (int ni = 0; ni < 4; ++ni) {
            const int n = n0 + wc * 64 + ni * 16 + (lane & 15);
            const float bval = bias[n];
            #pragma unroll
            for (int j = 0; j < 4; ++j) {
                const int m = m0 + wr * 64 + mi * 16 + ((lane >> 4) << 2) + j;
                float val = acc[mi][ni][j] + bval;
                if constexpr (OMODE == 0) {
                    Cf[(size_t)m * N + n] = val;
                } else {
                    const int b = m >> 11, s = m & (Ssz - 1);
                    const int h = n >> 6, c = n & (dh - 1);
                    size_t idx;
                    if constexpr (OMODE == 1)
                        idx = (((size_t)(b * Hn + h)) * Ssz + s) * dh + c;
                    else
                        idx = (((size_t)(b * Hn + h)) * dh + c) * Ssz + s;
                    unsigned short hi, lo;
                    bf_split(val, hi, lo);
                    Chi[idx] = hi; Clo[idx] = lo;
                }
            }
        }
    }
}

// ---------- agent pooling: agent[bh,a,c] = mean_{j<8} qh[bh,a*8+j,c], split output ----------
__global__ __launch_bounds__(256)
void pool_agent(const unsigned short* __restrict__ qh_hi, const unsigned short* __restrict__ qh_lo,
                unsigned short* __restrict__ ag_hi, unsigned short* __restrict__ ag_lo)
{
    const int idx = blockIdx.x * 256 + threadIdx.x;
    const int c = idx & (dh - 1);
    const int a = (idx >> 6) & (An - 1);
    const int bh = idx >> 14;
    const size_t base = ((size_t)bh * Ssz + a * 8) * dh + c;
    float s = 0.f;
    #pragma unroll
    for (int j = 0; j < 8; ++j)
        s += bf2f(qh_hi[base + j * dh]) + bf2f(qh_lo[base + j * dh]);
    s *= 0.125f;
    unsigned short hi, lo;
    bf_split(s, hi, lo);
    ag_hi[idx] = hi; ag_lo[idx] = lo;
}

// ---------- flash stage-1: agent_v = softmax(agent . K^T) . V (online over S) ----------
// grid (An/64, B*H). block 256 (4 waves x 16 agents).
__global__ __launch_bounds__(256, 2)
void flash1(const unsigned short* __restrict__ ag_hi, const unsigned short* __restrict__ ag_lo,
            const unsigned short* __restrict__ kh_hi, const unsigned short* __restrict__ kh_lo,
            const unsigned short* __restrict__ vt_hi_g, const unsigned short* __restrict__ vt_lo_g,
            unsigned short* __restrict__ avt_hi, unsigned short* __restrict__ avt_lo)
{
    __shared__ unsigned short lds[32768];   // 64 KB
    unsigned short* agh = lds;              // [64][64]
    unsigned short* agl = lds + 4096;
    unsigned short* kth = lds + 8192;       // [64][64]
    unsigned short* ktl = lds + 12288;
    unsigned short* vth = lds + 16384;      // [64 d][64 s]
    unsigned short* vtl = lds + 20480;
    // per-wave P: [16 a][64 s] hi/lo
    const int t = threadIdx.x;
    const int lane = t & 63, w = t >> 6;
    unsigned short* pwh = lds + 24576 + w * 2048;
    unsigned short* pwl = pwh + 1024;

    const int bh = blockIdx.y;
    const int a0 = blockIdx.x * 64;

    // stage this block's 64 agents
    stage_tile<3, 2>(ag_hi + ((size_t)bh * An + a0) * dh, dh, agh, t);
    stage_tile<3, 2>(ag_lo + ((size_t)bh * An + a0) * dh, dh, agl, t);

    f32x4 O[4];
    #pragma unroll
    for (int i = 0; i < 4; ++i) O[i] = f32x4{0.f, 0.f, 0.f, 0.f};
    float m_run = -INFINITY, l_run = 0.f;

    bf16x8 bqh[2], bql[2];
    bool haveQ = false;

    for (int s0 = 0; s0 < Ssz; s0 += 64) {
        stage_tile<3, 2>(kh_hi + ((size_t)bh * Ssz + s0) * dh, dh, kth, t);
        stage_tile<3, 2>(kh_lo + ((size_t)bh * Ssz + s0) * dh, dh, ktl, t);
        stage_tile<3, 2>(vt_hi_g + (size_t)bh * dh * Ssz + s0, Ssz, vth, t);
        stage_tile<3, 2>(vt_lo_g + (size_t)bh * dh * Ssz + s0, Ssz, vtl, t);
        __syncthreads();

        if (!haveQ) {
            #pragma unroll
            for (int ks = 0; ks < 2; ++ks) {
                bqh[ks] = fragR<64>(agh, w * 16 + (lane & 15), ks, lane);
                bql[ks] = fragR<64>(agl, w * 16 + (lane & 15), ks, lane);
            }
            haveQ = true;
        }

        // QK^T (swapped): acc col = agent (lane&15), row = s
        f32x4 sc[4];
        #pragma unroll
        for (int si = 0; si < 4; ++si) sc[si] = f32x4{0.f, 0.f, 0.f, 0.f};
        #pragma unroll
        for (int si = 0; si < 4; ++si)
            #pragma unroll
            for (int ks = 0; ks < 2; ++ks) {
                bf16x8 ah = fragR<64>(kth, si * 16 + (lane & 15), ks, lane);
                bf16x8 al = fragR<64>(ktl, si * 16 + (lane & 15), ks, lane);
                sc[si] = __builtin_amdgcn_mfma_f32_16x16x32_bf16(ah, bqh[ks], sc[si], 0, 0, 0);
                sc[si] = __builtin_amdgcn_mfma_f32_16x16x32_bf16(ah, bql[ks], sc[si], 0, 0, 0);
                sc[si] = __builtin_amdgcn_mfma_f32_16x16x32_bf16(al, bqh[ks], sc[si], 0, 0, 0);
            }

        // online softmax over s (rows) for this wave's agent = lane&15
        float tmax = -INFINITY;
        #pragma unroll
        for (int si = 0; si < 4; ++si)
            #pragma unroll
            for (int j = 0; j < 4; ++j) {
                sc[si][j] *= 0.125f;
                tmax = fmaxf(tmax, sc[si][j]);
            }
        tmax = fmaxf(tmax, __shfl_xor(tmax, 16));
        tmax = fmaxf(tmax, __shfl_xor(tmax, 32));
        float newm = fmaxf(m_run, tmax);
        float fac = __expf(m_run - newm);
        float tsum = 0.f;
        #pragma unroll
        for (int si = 0; si < 4; ++si)
            #pragma unroll
            for (int j = 0; j < 4; ++j) {
                float p = __expf(sc[si][j] - newm);
                sc[si][j] = p;
                tsum += p;
            }
        tsum += __shfl_xor(tsum, 16);
        tsum += __shfl_xor(tsum, 32);
        l_run = l_run * fac + tsum;
        m_run = newm;

        // write P (transposed into [a][s]) packed b64, swizzled
        const int aloc = lane & 15;
        #pragma unroll
        for (int si = 0; si < 4; ++si) {
            ushort4 h4, l4;
            bf_split(sc[si][0], h4.x, l4.x);
            bf_split(sc[si][1], h4.y, l4.y);
            bf_split(sc[si][2], h4.z, l4.z);
            bf_split(sc[si][3], h4.w, l4.w);
            int baseS = si * 16 + ((lane >> 4) << 2);
            int addr = aloc * 64 + (baseS ^ ((aloc & 7) << 3));
            *reinterpret_cast<ushort4*>(pwh + addr) = h4;
            *reinterpret_cast<ushort4*>(pwl + addr) = l4;
        }

        // rescale O
        float fj[4];
        #pragma unroll
        for (int j = 0; j < 4; ++j) fj[j] = __shfl(fac, ((lane >> 4) << 2) + j);
        #pragma unroll
        for (int di = 0; di < 4; ++di)
            #pragma unroll
            for (int j = 0; j < 4; ++j) O[di][j] *= fj[j];

        // PV: O[a][d] += P[a][s] * Vt[d][s]
        #pragma unroll
        for (int ks = 0; ks < 2; ++ks) {
            bf16x8 pah = fragR<64>(pwh, lane & 15, ks, lane);
            bf16x8 pal = fragR<64>(pwl, lane & 15, ks, lane);
            #pragma unroll
            for (int di = 0; di < 4; ++di) {
                bf16x8 vh = fragR<64>(vth, di * 16 + (lane & 15), ks, lane);
                bf16x8 vl = fragR<64>(vtl, di * 16 + (lane & 15), ks, lane);
                O[di] = __builtin_amdgcn_mfma_f32_16x16x32_bf16(pah, vh, O[di], 0, 0, 0);
                O[di] = __builtin_amdgcn_mfma_f32_16x16x32_bf16(pah, vl, O[di], 0, 0, 0);
                O[di] = __builtin_amdgcn_mfma_f32_16x16x32_bf16(pal, vh, O[di], 0, 0, 0);
            }
        }
        __syncthreads();
    }

    // epilogue: normalize, write agent_v transposed [bh][d][a] split bf16
    float lj[4];
    #pragma unroll
    for (int j = 0; j < 4; ++j) lj[j] = __shfl(l_run, ((lane >> 4) << 2) + j);
    #pragma unroll
    for (int di = 0; di < 4; ++di)
        #pragma unroll
        for (int j = 0; j < 4; ++j) {
            float val = O[di][j] / lj[j];
            int d = di * 16 + (lane & 15);
            int aG = a0 + w * 16 + ((lane >> 4) << 2) + j;
            size_t idx = ((size_t)bh * dh + d) * An + aG;
            unsigned short hi, lo;
            bf_split(val, hi, lo);
            avt_hi[idx] = hi; avt_lo[idx] = lo;
        }
}

// ---------- flash stage-2: q_attn = softmax(qh . agent^T); out_h = q_attn . agent_v ----------
// grid (Ssz/64, B*H). block 256 (4 waves x 16 s-rows).
__global__ __launch_bounds__(256, 1)
void flash2(const unsigned short* __restrict__ qh_hi, const unsigned short* __restrict__ qh_lo,
            const unsigned short* __restrict__ ag_hi, const unsigned short* __restrict__ ag_lo,
            const unsigned short* __restrict__ avt_hi, const unsigned short* __restrict__ avt_lo,
            float* __restrict__ q_attn,
            unsigned short* __restrict__ xo_hi, unsigned short* __restrict__ xo_lo)
{
    __shared__ unsigned short lds[65536];   // 128 KB
    unsigned short* agh = lds;              // [256][64] agents; reused as avt [64][256]
    unsigned short* agl = lds + 16384;
    unsigned short* qhh = lds + 32768;      // [64][64] (overlaps wave-0 P; barrier-protected)
    unsigned short* qhl = lds + 36864;

    const int t = threadIdx.x;
    const int lane = t & 63, w = t >> 6;
    unsigned short* pwh = lds + 32768 + w * 8192;   // [16 s][256 a]
    unsigned short* pwl = pwh + 4096;

    const int bh = blockIdx.y;
    const int s0 = blockIdx.x * 64;

    stage_tile<3, 8>(ag_hi + (size_t)bh * An * dh, dh, agh, t);
    stage_tile<3, 8>(ag_lo + (size_t)bh * An * dh, dh, agl, t);
    stage_tile<3, 2>(qh_hi + ((size_t)bh * Ssz + s0) * dh, dh, qhh, t);
    stage_tile<3, 2>(qh_lo + ((size_t)bh * Ssz + s0) * dh, dh, qhl, t);
    __syncthreads();

    // hoist qh fragments (b-operand), then barrier so P-writes can reuse qh LDS
    bf16x8 bqh[2], bql[2];
    #pragma unroll
    for (int ks = 0; ks < 2; ++ks) {
        bqh[ks] = fragR<64>(qhh, w * 16 + (lane & 15), ks, lane);
        bql[ks] = fragR<64>(qhl, w * 16 + (lane & 15), ks, lane);
    }
    __syncthreads();

    // QK^T (swapped): acc col = s (lane&15), rows = a
    f32x4 acc[16];
    #pragma unroll
    for (int ai = 0; ai < 16; ++ai) acc[ai] = f32x4{0.f, 0.f, 0.f, 0.f};
    #pragma unroll
    for (int ai = 0; ai < 16; ++ai)
        #pragma unroll
        for (int ks = 0; ks < 2; ++ks) {
            bf16x8 ah = fragR<64>(agh, ai * 16 + (lane & 15), ks, lane);
            bf16x8 al = fragR<64>(agl, ai * 16 + (lane & 15), ks, lane);
            acc[ai] = __builtin_amdgcn_mfma_f32_16x16x32_bf16(ah, bqh[ks], acc[ai], 0, 0, 0);
            acc[ai] = __builtin_amdgcn_mfma_f32_16x16x32_bf16(ah, bql[ks], acc[ai], 0, 0, 0);
            acc[ai] = __builtin_amdgcn_mfma_f32_16x16x32_bf16(al, bqh[ks], acc[ai], 0, 0, 0);
        }

    // exact softmax over a for s = lane&15
    float mx = -INFINITY;
    #pragma unroll
    for (int ai = 0; ai < 16; ++ai)
        #pragma unroll
        for (int j = 0; j < 4; ++j) {
            acc[ai][j] *= 0.125f;
            mx = fmaxf(mx, acc[ai][j]);
        }
    mx = fmaxf(mx, __shfl_xor(mx, 16));
    mx = fmaxf(mx, __shfl_xor(mx, 32));
    float sum = 0.f;
    #pragma unroll
    for (int ai = 0; ai < 16; ++ai)
        #pragma unroll
        for (int j = 0; j < 4; ++j) {
            float p = __expf(acc[ai][j] - mx);
            acc[ai][j] = p;
            sum += p;
        }
    sum += __shfl_xor(sum, 16);
    sum += __shfl_xor(sum, 32);
    const float inv = 1.0f / sum;

    // write q_attn (normalized, fp32, coalesced float4) and P to LDS
    {
        const int sG = s0 + w * 16 + (lane & 15);
        float* qrow = q_attn + ((size_t)bh * Ssz + sG) * An;
        const int sl = lane & 15;
        #pragma unroll
        for (int ai = 0; ai < 16; ++ai) {
            float4 o;
            o.x = acc[ai][0] * inv; o.y = acc[ai][1] * inv;
            o.z = acc[ai][2] * inv; o.w = acc[ai][3] * inv;
            *reinterpret_cast<float4*>(qrow + ai * 16 + ((lane >> 4) << 2)) = o;
            ushort4 h4, l4;
            bf_split(o.x, h4.x, l4.x);
            bf_split(o.y, h4.y, l4.y);
            bf_split(o.z, h4.z, l4.z);
            bf_split(o.w, h4.w, l4.w);
            int baseA = ai * 16 + ((lane >> 4) << 2);
            int addr = sl * 256 + (baseA ^ ((sl & 7) << 3));
            *reinterpret_cast<ushort4*>(pwh + addr) = h4;
            *reinterpret_cast<ushort4*>(pwl + addr) = l4;
        }
    }
    __syncthreads();

    // restage agent_v^T [64 d][256 a] into agent region
    stage_tile<5, 8>(avt_hi + (size_t)bh * dh * An, An, agh, t);
    stage_tile<5, 8>(avt_lo + (size_t)bh * dh * An, An, agl, t);
    __syncthreads();

    // PV: O[s][d] = sum_a P[s][a] * avt[d][a]
    f32x4 O[4];
    #pragma unroll
    for (int i = 0; i < 4; ++i) O[i] = f32x4{0.f, 0.f, 0.f, 0.f};
    #pragma unroll
    for (int ks = 0; ks < 8; ++ks) {
        bf16x8 pah = fragR<256>(pwh, lane & 15, ks, lane);
        bf16x8 pal = fragR<256>(pwl, lane & 15, ks, lane);
        #pragma unroll
        for (int di = 0; di < 4; ++di) {
            bf16x8 avh = fragR<256>(agh, di * 16 + (lane & 15), ks, lane);
            bf16x8 avl = fragR<256>(agl, di * 16 + (lane & 15), ks, lane);
            O[di] = __builtin_amdgcn_mfma_f32_16x16x32_bf16(pah, avh, O[di], 0, 0, 0);
            O[di] = __builtin_amdgcn_mfma_f32_16x16x32_bf16(pah, avl, O[di], 0, 0, 0);
            O[di] = __builtin_amdgcn_mfma_f32_16x16x32_bf16(pal, avh, O[di], 0, 0, 0);
        }
    }

    // epilogue: write out_h split bf16 into [B,S,D] head-merged
    const int b = bh >> 4, h = bh & (Hn - 1);
    #pragma unroll
    for (int di = 0; di < 4; ++di)
        #pragma unroll
        for (int j = 0; j < 4; ++j) {
            float val = O[di][j];
            int sG = s0 + w * 16 + ((lane >> 4) << 2) + j;
            int dfull = h * dh + di * 16 + (lane & 15);
            size_t idx = ((size_t)b * Ssz + sG) * Dsz + dfull;
            unsigned short hi, lo;
            bf_split(val, hi, lo);
            xo_hi[idx] = hi; xo_lo[idx] = lo;
        }
}

extern "C" void kernel_launch(void* const* d_in, const int* in_sizes, int n_in,
                              void* d_out, int out_size, void* d_ws, size_t ws_size,
                              hipStream_t stream)
{
    const float* q  = (const float*)d_in[0];
    const float* k  = (const float*)d_in[1];
    const float* v  = (const float*)d_in[2];
    const float* Wq = (const float*)d_in[3];
    const float* bq = (const float*)d_in[4];
    const float* Wk = (const float*)d_in[5];
    const float* bk = (const float*)d_in[6];
    const float* Wv = (const float*)d_in[7];
    const float* bv = (const float*)d_in[8];
    const float* Wo = (const float*)d_in[9];
    const float* bo = (const float*)d_in[10];

    constexpr size_t BSD = (size_t)Bsz * Ssz * Dsz;   // 8,388,608
    constexpr size_t DD  = (size_t)Dsz * Dsz;          // 1,048,576
    constexpr size_t AGD = (size_t)Bsz * Hn * An * dh; // 1,048,576

    float* out    = (float*)d_out;
    float* q_attn = out + BSD;

    unsigned short* u = (unsigned short*)d_ws;
    unsigned short* x_hi   = u;                 // [B,S,D] bf16 (also out_h buffer)
    unsigned short* x_lo   = x_hi + BSD;
    unsigned short* qh_hi  = x_lo + BSD;        // [B,H,S,dh]
    unsigned short* qh_lo  = qh_hi + BSD;
    unsigned short* kh_hi  = qh_lo + BSD;
    unsigned short* kh_lo  = kh_hi + BSD;
    unsigned short* vt_hi  = kh_lo + BSD;       // [B,H,dh,S]
    unsigned short* vt_lo  = vt_hi + BSD;
    unsigned short* w_hi   = vt_lo + BSD;       // [D,D]
    unsigned short* w_lo   = w_hi + DD;
    unsigned short* ag_hi  = w_lo + DD;         // [B,H,A,dh]
    unsigned short* ag_lo  = ag_hi + AGD;
    unsigned short* avt_hi = ag_lo + AGD;       // [B,H,dh,A]
    unsigned short* avt_lo = avt_hi + AGD;

    const int M = Bsz * Ssz;                    // 8192
    dim3 gmfma(Dsz / MT, M / MT, 1);            // (8, 64)

    // Q projection
    split_kernel<<<BSD / 1024, 256, 0, stream>>>(q, x_hi, x_lo, BSD / 4);
    split_kernel<<<DD / 1024, 256, 0, stream>>>(Wq, w_hi, w_lo, DD / 4);
    gemm_nt_mfma3<1><<<gmfma, 256, 0, stream>>>(x_hi, x_lo, w_hi, w_lo, bq, nullptr, qh_hi, qh_lo, Dsz, Dsz);
    // K projection
    split_kernel<<<BSD / 1024, 256, 0, stream>>>(k, x_hi, x_lo, BSD / 4);
    split_kernel<<<DD / 1024, 256, 0, stream>>>(Wk, w_hi, w_lo, DD / 4);
    gemm_nt_mfma3<1><<<gmfma, 256, 0, stream>>>(x_hi, x_lo, w_hi, w_lo, bk, nullptr, kh_hi, kh_lo, Dsz, Dsz);
    // V projection (transposed head-split output)
    split_kernel<<<BSD / 1024, 256, 0, stream>>>(v, x_hi, x_lo, BSD / 4);
    split_kernel<<<DD / 1024, 256, 0, stream>>>(Wv, w_hi, w_lo, DD / 4);
    gemm_nt_mfma3<2><<<gmfma, 256, 0, stream>>>(x_hi, x_lo, w_hi, w_lo, bv, nullptr, vt_hi, vt_lo, Dsz, Dsz);

    // agent pooling (split output)
    pool_agent<<<AGD / 256, 256, 0, stream>>>(qh_hi, qh_lo, ag_hi, ag_lo);

    // stage 1: flash agent attention -> agent_v^T
    flash1<<<dim3(An / 64, Bsz * Hn), 256, 0, stream>>>(
        ag_hi, ag_lo, kh_hi, kh_lo, vt_hi, vt_lo, avt_hi, avt_lo);

    // stage 2: q attends agents -> q_attn (output) + out_h (split, into x buffer)
    flash2<<<dim3(Ssz / 64, Bsz * Hn), 256, 0, stream>>>(
        qh_hi, qh_lo, ag_hi, ag_lo, avt_hi, avt_lo, q_attn, x_hi, x_lo);

    // output projection
    split_kernel<<<DD / 1024, 256, 0, stream>>>(Wo, w_hi, w_lo, DD / 4);
    gemm_nt_mfma3<0><<<gmfma, 256, 0, stream>>>(x_hi, x_lo, w_hi, w_lo, bo, out, nullptr, nullptr, Dsz, Dsz);
}